// Round 3
// baseline (617.355 us; speedup 1.0000x reference)
//
#include <hip/hip_runtime.h>

// Problem: features (1,512,512,256) f32, superpixel (512,512) int (harness
// delivers int32), w_node (21,256) f32.
//   out[sp][c] = (mean over pixels with label sp of features[pixel]) . w_node[c]
// NUM_SP = 1024, F = 256, C = 21, n_pix = 262144.
//
// Streaming design (no sort, no gather, no global atomics):
//   k1 hist:  128 blocks, LDS histogram -> slab[b][label] plain stores.
//   k2 accum: grid = 8 col-slices x 32 pixel-chunks (256 blocks, 1/CU,
//             all co-resident). Block (s,p) streams its pixels' 128 B
//             column-segment (full-cacheline reads) and ds_add_f32's into a
//             bank-swizzled LDS accumulator acc[1024][33] (132 KB of the
//             160 KB CU budget; stride 33 -> bank = (label+col)%32, spreads
//             random labels over all banks). Writes partial[s][p][1024][32].
//   k3 final: 1 block per label: count = sum slab column, col-sums over the
//             32 chunk-partials, mean, fused 21-class linear.

#define NSP 1024
#define FDIM 256
#define NHB 128      // hist blocks
#define NSLICE 8     // feature-column slices (32 cols = 128 B each)
#define NCHUNK 32    // pixel chunks
#define SCOLS 32     // cols per slice
#define STRIDE 33    // LDS row stride: bank = (label*33 + c) % 32 = (label+c)%32

__global__ __launch_bounds__(256) void hist_kernel(
    const int* __restrict__ sp, int n, int* __restrict__ slab) {
    __shared__ int lh[NSP];
    const int b = blockIdx.x;
    for (int t = threadIdx.x; t < NSP; t += 256) lh[t] = 0;
    __syncthreads();
    const int chunk = n / NHB;
    const int begin = b * chunk;
    const int end = begin + chunk;
    for (int i = begin + (int)threadIdx.x; i < end; i += 256)
        atomicAdd(&lh[sp[i]], 1);
    __syncthreads();
    for (int t = threadIdx.x; t < NSP; t += 256)
        slab[b * NSP + t] = lh[t];  // coalesced plain store
}

// grid = NSLICE*NCHUNK blocks x 1024 threads. Block bid: s = bid>>5 (slice),
// p = bid&31 (pixel chunk of 8192). Thread t: pixel sub-index t>>3 within a
// 128-pixel group, cols (t&7)*4 .. +4 within the slice.
__global__ __launch_bounds__(1024) void accum_kernel(
    const float* __restrict__ feats, const int* __restrict__ sp,
    float* __restrict__ partial, int n) {
    __shared__ float acc[NSP * STRIDE];  // 132 KB
    const int bid = blockIdx.x;
    const int s = bid >> 5;
    const int p = bid & 31;
    const int t = (int)threadIdx.x;

    for (int i = t; i < NSP * STRIDE; i += 1024) acc[i] = 0.f;
    __syncthreads();

    const int chunk = n / NCHUNK;  // 8192
    const int base_pix = p * chunk;
    const int sub = t >> 3;        // 0..127
    const int c4 = (t & 7) * 4;    // col group within slice
    const float* fbase = feats + (size_t)s * SCOLS + c4;

    #pragma unroll 4
    for (int g = 0; g < chunk; g += 128) {
        const int pix = base_pix + g + sub;
        const int lab = sp[pix];
        const float4 v = *(const float4*)(fbase + (size_t)pix * FDIM);
        float* row = &acc[lab * STRIDE + c4];
        atomicAdd(&row[0], v.x);  // ds_add_f32, banks spread by label swizzle
        atomicAdd(&row[1], v.y);
        atomicAdd(&row[2], v.z);
        atomicAdd(&row[3], v.w);
    }
    __syncthreads();

    // partial[s][p][label][32], coalesced stores; de-stride 33 -> 32.
    float* dst = partial + (size_t)bid * (NSP * SCOLS);
    for (int i = t; i < NSP * SCOLS; i += 1024) {
        const int lab = i >> 5, c = i & 31;
        dst[i] = acc[lab * STRIDE + c];
    }
}

// 1 block per label. Thread t owns feature col t (= slice t>>5, col t&31).
__global__ __launch_bounds__(256) void final_kernel(
    const float* __restrict__ partial, const int* __restrict__ slab,
    const float* __restrict__ w, float* __restrict__ out, int C) {
    __shared__ float mean_s[FDIM];
    __shared__ int cnt_s[NHB];
    const int L = blockIdx.x;
    const int t = (int)threadIdx.x;

    if (t < NHB) cnt_s[t] = slab[t * NSP + L];
    __syncthreads();
    for (int off = NHB / 2; off > 0; off >>= 1) {
        if (t < off) cnt_s[t] += cnt_s[t + off];
        __syncthreads();
    }
    const int n = cnt_s[0];

    const int s = t >> 5, c = t & 31;
    float sum = 0.f;
    #pragma unroll 4
    for (int p = 0; p < NCHUNK; ++p)
        sum += partial[((size_t)(s * NCHUNK + p) * NSP + L) * SCOLS + c];
    const float scale = (n > 0) ? 1.0f / (float)n : 0.0f;
    mean_s[t] = sum * scale;  // col t
    __syncthreads();

    const int lane = t & 63, wave = t >> 6;
    const float4 m = ((const float4*)mean_s)[lane];
    for (int cc = wave; cc < C; cc += 4) {
        const float4 w4 = ((const float4*)(w + (size_t)cc * FDIM))[lane];
        float pr = m.x * w4.x + m.y * w4.y + m.z * w4.z + m.w * w4.w;
        #pragma unroll
        for (int off = 32; off > 0; off >>= 1) pr += __shfl_down(pr, off, 64);
        if (lane == 0) out[L * C + cc] = pr;
    }
}

extern "C" void kernel_launch(void* const* d_in, const int* in_sizes, int n_in,
                              void* d_out, int out_size, void* d_ws,
                              size_t ws_size, hipStream_t stream) {
    const float* feats = (const float*)d_in[0];
    const int* sp = (const int*)d_in[1];
    const float* w = (const float*)d_in[2];
    float* out = (float*)d_out;

    const int n_pix = in_sizes[1];     // 262144
    const int C = in_sizes[2] / FDIM;  // 21

    // Workspace (every word written before read; 0xAA poison irrelevant):
    //   [0, 512K)       slab    int[NHB][NSP]
    //   [1M, 1M+32M)    partial float[NSLICE][NCHUNK][NSP][SCOLS]
    char* ws = (char*)d_ws;
    int* slab = (int*)(ws);
    float* partial = (float*)(ws + (1 << 20));

    hist_kernel<<<NHB, 256, 0, stream>>>(sp, n_pix, slab);
    accum_kernel<<<NSLICE * NCHUNK, 1024, 0, stream>>>(feats, sp, partial,
                                                       n_pix);
    final_kernel<<<NSP, 256, 0, stream>>>(partial, slab, w, out, C);
}

// Round 4
// 391.039 us; speedup vs baseline: 1.5788x; 1.5788x over previous
//
#include <hip/hip_runtime.h>

// Problem: features (1,512,512,256) f32, superpixel (512,512) int32, w_node (21,256) f32
//   out[sp][c] = (mean over pixels with label sp of features[pixel]) . w_node[c]
// NUM_SP = 1024, F = 256, C = 21, n_pix = 262144.
//
// Counting-sort + gather (zero global atomics; LDS fp32 atomics measured at
// ~3.2 cyc/lane on gfx950 r3 — avoided everywhere):
//   k1 hist:    128 blocks, LDS int histogram -> slab[b][label] plain stores
//   k2 scan:    1 block x 1024 thr: per-label exclusive prefix down the slab
//               column (x4 unrolled) + Hillis-Steele scan of totals -> starts
//   k3 scatter: 128 blocks, LDS cursors; LDS int atomics for rank only
//   k4 reduce:  1 block per superpixel, 512 thr (8 waves; 4 blocks/CU = 32
//               waves/CU), idx slice cached in LDS, wave-wide float4 row
//               gathers (1 KB contiguous), per-wave partials + tree combine,
//               fused /count + 21-class linear.

#define NSP 1024
#define FDIM 256
#define NHB 128
#define IDX_CAP 2048

__global__ __launch_bounds__(256) void hist_kernel(
    const int* __restrict__ sp, int n, int* __restrict__ slab) {
    __shared__ int lh[NSP];
    const int b = blockIdx.x;
    for (int t = threadIdx.x; t < NSP; t += 256) lh[t] = 0;
    __syncthreads();
    const int chunk = n / NHB;
    const int begin = b * chunk;
    const int end = begin + chunk;
    for (int i = begin + (int)threadIdx.x; i < end; i += 256)
        atomicAdd(&lh[sp[i]], 1);  // int LDS atomic, light contention
    __syncthreads();
    for (int t = threadIdx.x; t < NSP; t += 256)
        slab[b * NSP + t] = lh[t];  // coalesced plain store
}

__global__ __launch_bounds__(NSP) void scan_kernel(
    int* __restrict__ slab, int* __restrict__ starts, int* __restrict__ counts) {
    __shared__ int buf[NSP];
    const int t = threadIdx.x;
    int running = 0;
    #pragma unroll 1
    for (int b = 0; b < NHB; b += 4) {  // x4: 4 independent loads in flight
        int v0 = slab[(b + 0) * NSP + t];
        int v1 = slab[(b + 1) * NSP + t];
        int v2 = slab[(b + 2) * NSP + t];
        int v3 = slab[(b + 3) * NSP + t];
        slab[(b + 0) * NSP + t] = running; running += v0;
        slab[(b + 1) * NSP + t] = running; running += v1;
        slab[(b + 2) * NSP + t] = running; running += v2;
        slab[(b + 3) * NSP + t] = running; running += v3;
    }
    counts[t] = running;
    buf[t] = running;
    __syncthreads();
    for (int off = 1; off < NSP; off <<= 1) {  // Hillis-Steele inclusive
        int add = (t >= off) ? buf[t - off] : 0;
        __syncthreads();
        buf[t] += add;
        __syncthreads();
    }
    starts[t] = buf[t] - running;  // exclusive
}

__global__ __launch_bounds__(256) void scatter_kernel(
    const int* __restrict__ sp, int n, const int* __restrict__ slab,
    const int* __restrict__ starts, int* __restrict__ order) {
    __shared__ int cursor[NSP];
    const int b = blockIdx.x;
    for (int t = threadIdx.x; t < NSP; t += 256)
        cursor[t] = slab[b * NSP + t] + starts[t];
    __syncthreads();
    const int chunk = n / NHB;
    const int begin = b * chunk;
    const int end = begin + chunk;
    for (int i = begin + (int)threadIdx.x; i < end; i += 256) {
        int pos = atomicAdd(&cursor[sp[i]], 1);  // int LDS atomic only
        order[pos] = i;
    }
}

// grid = NSP blocks x 512 threads (8 waves). Block b owns superpixel b.
// __launch_bounds__(512, 8): 8 waves/SIMD -> 4 blocks/CU -> 32 waves/CU,
// exactly covering grid 1024 on 256 CUs. ~48 VGPRs needed, no spill risk.
__global__ __launch_bounds__(512, 8) void reduce_matmul_kernel(
    const float* __restrict__ feats, const int* __restrict__ order,
    const int* __restrict__ starts, const int* __restrict__ counts,
    const float* __restrict__ w, float* __restrict__ out, int C) {
    __shared__ int idx_lds[IDX_CAP];   // 8 KB
    __shared__ float part[8 * FDIM];   // 8 KB per-wave partials
    __shared__ float mean_s[FDIM];
    const int b = blockIdx.x;
    const int tid = (int)threadIdx.x;
    const int lane = tid & 63;
    const int wave = tid >> 6;

    const int start = starts[b];
    const int n = counts[b];
    const bool cached = (n <= IDX_CAP);  // n ~ 256 +- 16; always true w.h.p.

    if (cached)
        for (int i = tid; i < n; i += 512) idx_lds[i] = order[start + i];
    __syncthreads();

    // Lane covers feature cols [4*lane, 4*lane+4). Wave strides 32 rows
    // (8 waves x 4 rows); 4 independent 1 KB row-gathers in flight per wave
    // (4 KB/wave x 32 waves/CU = 128 KB in flight vs ~9 KB needed at peak BW).
    float a0x = 0.f, a0y = 0.f, a0z = 0.f, a0w = 0.f;
    float a1x = 0.f, a1y = 0.f, a1z = 0.f, a1w = 0.f;

    int pos = wave * 4;
    for (; pos + 3 < n; pos += 32) {
        int i0, i1, i2, i3;
        if (cached) {
            i0 = idx_lds[pos + 0]; i1 = idx_lds[pos + 1];
            i2 = idx_lds[pos + 2]; i3 = idx_lds[pos + 3];
        } else {
            i0 = order[start + pos + 0]; i1 = order[start + pos + 1];
            i2 = order[start + pos + 2]; i3 = order[start + pos + 3];
        }
        float4 v0 = ((const float4*)(feats + (size_t)i0 * FDIM))[lane];
        float4 v1 = ((const float4*)(feats + (size_t)i1 * FDIM))[lane];
        float4 v2 = ((const float4*)(feats + (size_t)i2 * FDIM))[lane];
        float4 v3 = ((const float4*)(feats + (size_t)i3 * FDIM))[lane];
        a0x += v0.x; a0y += v0.y; a0z += v0.z; a0w += v0.w;
        a1x += v1.x; a1y += v1.y; a1z += v1.z; a1w += v1.w;
        a0x += v2.x; a0y += v2.y; a0z += v2.z; a0w += v2.w;
        a1x += v3.x; a1y += v3.y; a1z += v3.z; a1w += v3.w;
    }
    for (; pos < n; ++pos) {  // tail (at most one wave enters)
        int idx = cached ? idx_lds[pos] : order[start + pos];
        float4 v = ((const float4*)(feats + (size_t)idx * FDIM))[lane];
        a0x += v.x; a0y += v.y; a0z += v.z; a0w += v.w;
    }
    a0x += a1x; a0y += a1y; a0z += a1z; a0w += a1w;

    // Per-wave partial -> plain b128 store (16B/lane phase pattern,
    // conflict-free), then 256-thread tree sum. No LDS atomics.
    float4 pv; pv.x = a0x; pv.y = a0y; pv.z = a0z; pv.w = a0w;
    ((float4*)&part[wave * FDIM])[lane] = pv;
    __syncthreads();

    if (tid < FDIM) {
        float s = 0.f;
        #pragma unroll
        for (int wv = 0; wv < 8; ++wv) s += part[wv * FDIM + tid];
        const float scale = (n > 0) ? 1.0f / (float)n : 0.0f;
        mean_s[tid] = s * scale;
    }
    __syncthreads();

    // Fused linear: 8 waves split the C classes; shuffle-reduce each dot.
    const float4 m = ((const float4*)mean_s)[lane];
    for (int c = wave; c < C; c += 8) {
        const float4 w4 = ((const float4*)(w + (size_t)c * FDIM))[lane];
        float p = m.x * w4.x + m.y * w4.y + m.z * w4.z + m.w * w4.w;
        #pragma unroll
        for (int off = 32; off > 0; off >>= 1) p += __shfl_down(p, off, 64);
        if (lane == 0) out[b * C + c] = p;
    }
}

extern "C" void kernel_launch(void* const* d_in, const int* in_sizes, int n_in,
                              void* d_out, int out_size, void* d_ws,
                              size_t ws_size, hipStream_t stream) {
    const float* feats = (const float*)d_in[0];
    const int* sp = (const int*)d_in[1];
    const float* w = (const float*)d_in[2];
    float* out = (float*)d_out;

    const int n_pix = in_sizes[1];     // 262144 (divisible by NHB=128)
    const int C = in_sizes[2] / FDIM;  // 21

    // Workspace (every word written before read; 0xAA poison irrelevant):
    //   [0, 512K)      slab   int[NHB][NSP]
    //   [512K, +4K)    starts int[NSP]
    //   [516K, +4K)    counts int[NSP]
    //   [520K, +1M)    order  int[n_pix]
    char* ws = (char*)d_ws;
    int* slab = (int*)(ws);
    int* starts = (int*)(ws + 512 * 1024);
    int* counts = (int*)(ws + 516 * 1024);
    int* order = (int*)(ws + 520 * 1024);

    hist_kernel<<<NHB, 256, 0, stream>>>(sp, n_pix, slab);
    scan_kernel<<<1, NSP, 0, stream>>>(slab, starts, counts);
    scatter_kernel<<<NHB, 256, 0, stream>>>(sp, n_pix, slab, starts, order);
    reduce_matmul_kernel<<<NSP, 512, 0, stream>>>(feats, order, starts, counts,
                                                  w, out, C);
}

// Round 5
// 389.460 us; speedup vs baseline: 1.5852x; 1.0041x over previous
//
#include <hip/hip_runtime.h>

// Problem: features (1,512,512,256) f32, superpixel (512,512) int32 (harness
// casts int64->int32), w_node (21,256) f32.
//   out[sp][c] = (mean over pixels with label sp of features[pixel]) . w_node[c]
// NUM_SP = 1024, F = 256, C = 21, n_pix = 262144.
//
// Single fused kernel (r5). Rationale from r3/r4 forensics: harness fixed
// overhead ~257 us; r4's 4-kernel sort pipeline spent ~85 us on hist/scan/
// scatter scaffolding around a ~48 us roofline gather. The label array is
// 1 MB = L2-resident, so each block scans it directly instead of sorting:
//   grid = 256 blocks (1/CU) x 1024 threads; block b owns labels [4b, 4b+4).
//   Phase 1: int4-scan all labels (1 MB via L2, ~7 us/CU), append matching
//            pixel indices into 4 LDS lists (LDS int atomics, ~1024/block).
//   Phase 2: 4 waves per list gather feature rows (1 KB contiguous float4
//            loads, 4 rows in flight/wave), register-accumulate, per-wave
//            LDS partials, tree combine, /count, fused 21-class linear.
// Zero global atomics, zero workspace, one launch.

#define NSP 1024
#define FDIM 256
#define G 4        // labels per block
#define CAP 1024   // per-list LDS capacity (counts ~256+-50; 1024 is safe)

__global__ __launch_bounds__(1024, 4) void fused_segmean_linear_kernel(
    const float* __restrict__ feats, const int* __restrict__ sp,
    const float* __restrict__ wn, float* __restrict__ out, int n, int C) {
    __shared__ int list[G * CAP];       // 16 KB
    __shared__ int cnt[G];
    __shared__ float part[16 * FDIM];   // 16 KB per-wave partials
    __shared__ float mean_s[G * FDIM];  // 4 KB

    const int b = blockIdx.x;
    const int t = (int)threadIdx.x;
    const int lane = t & 63;
    const int wave = t >> 6;

    if (t < G) cnt[t] = 0;
    __syncthreads();

    // ---- Phase 1: scan labels (L2-resident), build per-label pixel lists.
    const int4* sp4 = (const int4*)sp;
    const int n4 = n >> 2;
    #pragma unroll 4
    for (int i = t; i < n4; i += 1024) {
        const int4 v = sp4[i];
        const int base = i << 2;
        if ((v.x >> 2) == b) { int p = atomicAdd(&cnt[v.x & 3], 1); if (p < CAP) list[(v.x & 3) * CAP + p] = base + 0; }
        if ((v.y >> 2) == b) { int p = atomicAdd(&cnt[v.y & 3], 1); if (p < CAP) list[(v.y & 3) * CAP + p] = base + 1; }
        if ((v.z >> 2) == b) { int p = atomicAdd(&cnt[v.z & 3], 1); if (p < CAP) list[(v.z & 3) * CAP + p] = base + 2; }
        if ((v.w >> 2) == b) { int p = atomicAdd(&cnt[v.w & 3], 1); if (p < CAP) list[(v.w & 3) * CAP + p] = base + 3; }
    }
    __syncthreads();

    // ---- Phase 2: gather + accumulate. Wave w serves list g = w>>2 with
    // 3 sibling waves (sub = w&3); lane covers cols [4*lane, 4*lane+4).
    const int g = wave >> 2;
    const int sub = wave & 3;
    const int ng = min(cnt[g], CAP);
    const int* mylist = &list[g * CAP];

    float a0x = 0.f, a0y = 0.f, a0z = 0.f, a0w = 0.f;
    float a1x = 0.f, a1y = 0.f, a1z = 0.f, a1w = 0.f;

    int pos = sub * 4;  // 4 waves x 4 rows = 16-row stride per list
    for (; pos + 3 < ng; pos += 16) {
        const int i0 = mylist[pos + 0];
        const int i1 = mylist[pos + 1];
        const int i2 = mylist[pos + 2];
        const int i3 = mylist[pos + 3];
        float4 v0 = ((const float4*)(feats + (size_t)i0 * FDIM))[lane];
        float4 v1 = ((const float4*)(feats + (size_t)i1 * FDIM))[lane];
        float4 v2 = ((const float4*)(feats + (size_t)i2 * FDIM))[lane];
        float4 v3 = ((const float4*)(feats + (size_t)i3 * FDIM))[lane];
        a0x += v0.x; a0y += v0.y; a0z += v0.z; a0w += v0.w;
        a1x += v1.x; a1y += v1.y; a1z += v1.z; a1w += v1.w;
        a0x += v2.x; a0y += v2.y; a0z += v2.z; a0w += v2.w;
        a1x += v3.x; a1y += v3.y; a1z += v3.z; a1w += v3.w;
    }
    for (; pos < ng; ++pos) {  // straddling wave finishes its partial group
        const int idx = mylist[pos];
        float4 v = ((const float4*)(feats + (size_t)idx * FDIM))[lane];
        a0x += v.x; a0y += v.y; a0z += v.z; a0w += v.w;
    }
    a0x += a1x; a0y += a1y; a0z += a1z; a0w += a1w;

    float4 pv; pv.x = a0x; pv.y = a0y; pv.z = a0z; pv.w = a0w;
    ((float4*)&part[wave * FDIM])[lane] = pv;
    __syncthreads();

    // ---- Combine 4 sibling-wave partials per list; scale to mean.
    {
        const int gg = t >> 8;        // 0..3
        const int col = t & 255;      // 0..255
        float s = part[(gg * 4 + 0) * FDIM + col] +
                  part[(gg * 4 + 1) * FDIM + col] +
                  part[(gg * 4 + 2) * FDIM + col] +
                  part[(gg * 4 + 3) * FDIM + col];
        const int cg = cnt[gg];
        mean_s[gg * FDIM + col] = (cg > 0) ? s / (float)cg : 0.f;
    }
    __syncthreads();

    // ---- Fused linear: 4 waves per list split the 21 classes.
    const float4 m = ((const float4*)&mean_s[g * FDIM])[lane];
    for (int c = sub; c < C; c += 4) {
        const float4 w4 = ((const float4*)(wn + (size_t)c * FDIM))[lane];
        float p = m.x * w4.x + m.y * w4.y + m.z * w4.z + m.w * w4.w;
        #pragma unroll
        for (int off = 32; off > 0; off >>= 1) p += __shfl_down(p, off, 64);
        if (lane == 0) out[(b * G + g) * C + c] = p;
    }
}

extern "C" void kernel_launch(void* const* d_in, const int* in_sizes, int n_in,
                              void* d_out, int out_size, void* d_ws,
                              size_t ws_size, hipStream_t stream) {
    const float* feats = (const float*)d_in[0];
    const int* sp = (const int*)d_in[1];
    const float* wn = (const float*)d_in[2];
    float* out = (float*)d_out;

    const int n_pix = in_sizes[1];     // 262144
    const int C = in_sizes[2] / FDIM;  // 21

    fused_segmean_linear_kernel<<<NSP / G, 1024, 0, stream>>>(feats, sp, wn,
                                                              out, n_pix, C);
}